// Round 7
// baseline (57.150 us; speedup 1.0000x reference)
//
#include <hip/hip_runtime.h>
#include <hip/hip_bf16.h>
#include <stdint.h>

// Problem constants (B=8, S=512, D=1024)
constexpr int N_TOK  = 4096;   // B*S
constexpr int D_DIM  = 1024;
constexpr int MASK_ID_V = 8192;

// Fast path: 256x256 tiles, 16 waves (4Mx4N), BK=64 as 2 halves of 32
constexpr int BM2  = 256;
constexpr int KT2  = D_DIM / 64;     // 16 K-tiles
constexpr int NSL2 = N_TOK / BM2;    // 16 col slices
constexpr int NPART = NSL2 * 4;      // 64 partials/row (4 wc-waves per slice)

// Fallback tiling (used only if ws too small)
constexpr int BM = 128, BN = 128, BK = 64;
constexpr int KST = D_DIM / BK;
constexpr int NSLICE_FB = 8;
constexpr int SLICE_W   = N_TOK / NSLICE_FB;
constexpr int CTS       = SLICE_W / BN;
constexpr int LDW       = BK + 8;
constexpr int NPART_FB  = NSLICE_FB * 2;

constexpr int FIN_BLOCKS = 256;

typedef __attribute__((ext_vector_type(4))) float f32x4;
typedef __attribute__((ext_vector_type(8))) short bf16x8;

__device__ __forceinline__ uint32_t pk2bf(float lo, float hi) {
    union { float f; uint32_t u; } a, b;
    a.f = lo; b.f = hi;
    uint32_t ua = (a.u + 0x7fffu + ((a.u >> 16) & 1u)) >> 16;
    uint32_t ub = (b.u + 0x7fffu + ((b.u >> 16) & 1u)) >> 16;
    return ua | (ub << 16);
}

__device__ __forceinline__ void async16(void* lds, const void* g) {
    __builtin_amdgcn_global_load_lds(
        (const __attribute__((address_space(1))) uint32_t*)g,
        (__attribute__((address_space(3))) uint32_t*)lds,
        16, 0, 0);
}

#define BAR   do { __builtin_amdgcn_s_barrier(); __builtin_amdgcn_sched_barrier(0); } while (0)

// ---------------------------------------------------------------------------
// Pass 1: fp32 -> bf16 pre-convert (once)
// ---------------------------------------------------------------------------
__global__ __launch_bounds__(256) void conv_bf16(
    const float* __restrict__ x, const float* __restrict__ e,
    ushort* __restrict__ xb, ushort* __restrict__ eb)
{
    constexpr int NCHUNK = N_TOK * D_DIM / 8;
    const int t0 = blockIdx.x * blockDim.x + threadIdx.x;
    const int stride = gridDim.x * blockDim.x;
    for (int c = t0; c < NCHUNK; c += stride) {
        float4 a0 = ((const float4*)x)[c * 2];
        float4 a1 = ((const float4*)x)[c * 2 + 1];
        uint4 p;
        p.x = pk2bf(a0.x, a0.y); p.y = pk2bf(a0.z, a0.w);
        p.z = pk2bf(a1.x, a1.y); p.w = pk2bf(a1.z, a1.w);
        ((uint4*)xb)[c] = p;

        float4 b0 = ((const float4*)e)[c * 2];
        float4 b1 = ((const float4*)e)[c * 2 + 1];
        uint4 q;
        q.x = pk2bf(b0.x, b0.y); q.y = pk2bf(b0.z, b0.w);
        q.z = pk2bf(b1.x, b1.y); q.w = pk2bf(b1.z, b1.w);
        ((uint4*)eb)[c] = q;
    }
}

// ---------------------------------------------------------------------------
// Pass 2: 256x256 GEMM, 16 waves, ONE barrier per K-tile, stage-after-barrier,
// compiler-scheduled ds_read<->MFMA interleave, swizzled LDS (conflict-free)
// ---------------------------------------------------------------------------
__global__ __launch_bounds__(1024, 4) void nce_gemm8(
    const ushort* __restrict__ xb,    // [N_TOK, D] bf16 keys
    const ushort* __restrict__ eb,    // [N_TOK, D] bf16 queries
    float* __restrict__ numer,
    float* __restrict__ pm,
    float* __restrict__ ps)
{
    __shared__ ushort As[2][2][8192];   // [buf][khalf][256*32]  64 KB
    __shared__ ushort Bs[2][2][8192];   // 64 KB  (total 128 KB)

    // Bijective XCD-chunked swizzle: each XCD -> two 4x4 tile-chunks
    const int bid   = blockIdx.x;
    const int sw    = (bid & 7) * 32 + (bid >> 3);
    const int chunk = sw >> 4, win = sw & 15;
    const int rb    = (chunk & 3) * 4 + (win & 3);
    const int cs    = (chunk >> 2) * 4 + (win >> 2);
    const int row0  = rb * BM2;
    const int col0  = cs * BM2;

    const int tid  = threadIdx.x;
    const int lane = tid & 63;
    const int wid  = tid >> 6;         // 0..15
    const int wr   = wid >> 2;         // 0..3  (M-warps)
    const int wc   = wid & 3;          // 0..3  (N-warps)
    const int l15  = lane & 15;
    const int lhi  = lane >> 4;        // 0..3

    // Staging addresses (per lane, loop-invariant). LDS dest is linear;
    // source is pre-swizzled: phys 16B-slot = logical ^ ((row>>1)&3).
    const int srow = wid * 16 + (lane >> 2);
    const int ssub = (lane & 3) ^ ((srow >> 1) & 3);
    const ushort* gA = eb + (size_t)(row0 + srow) * D_DIM + ssub * 8;
    const ushort* gB = xb + (size_t)(col0 + srow) * D_DIM + ssub * 8;
    ushort* ldsA = &As[0][0][0] + wid * 512;   // wave-uniform base
    ushort* ldsB = &Bs[0][0][0] + wid * 512;

    // Frag read offsets (elems) — swizzle slot is mf/nf-independent
    const int arow = wr * 64 + l15;
    const int aoff = arow * 32 + (lhi ^ ((arow >> 1) & 3)) * 8;
    const int brow = wc * 64 + l15;
    const int boff = brow * 32 + (lhi ^ ((brow >> 1) & 3)) * 8;

    f32x4 acc[4][4];
#pragma unroll
    for (int a = 0; a < 4; ++a)
#pragma unroll
        for (int b = 0; b < 4; ++b)
            acc[a][b] = f32x4{0.f, 0.f, 0.f, 0.f};

    // Prologue: stage K-tile 0 into buffer 0
    async16(ldsA + 0 * 8192, gA);
    async16(ldsB + 0 * 8192, gB);
    async16(ldsA + 1 * 8192, gA + 32);
    async16(ldsB + 1 * 8192, gB + 32);
    const ushort* gAn = gA + 64;
    const ushort* gBn = gB + 64;

    bf16x8 af[4], bq[4];

#pragma unroll 1
    for (int kt = 0; kt < KT2; ++kt) {
        const int c = kt & 1, n = c ^ 1;
        const bool pre = (kt < KT2 - 1);

        // Wave's own stages of tile kt are done -> barrier makes all visible.
        asm volatile("s_waitcnt vmcnt(0)" ::: "memory");
        BAR;

        // Stage tile kt+1 into buffer n. Safe: every wave has passed the
        // barrier, so no one is still reading buffer n (last read in kt-1).
        if (pre) {
            async16(ldsA + (n * 2 + 0) * 8192, gAn);
            async16(ldsB + (n * 2 + 0) * 8192, gBn);
            async16(ldsA + (n * 2 + 1) * 8192, gAn + 32);
            async16(ldsB + (n * 2 + 1) * 8192, gBn + 32);
            gAn += 64; gBn += 64;
        }

        // Compute both K-halves of buffer c; no forced lgkm drains — the
        // compiler interleaves ds_read/MFMA with fine-grained lgkmcnt.
        {
            const ushort* aB = &As[c][0][0] + aoff;
            const ushort* bB = &Bs[c][0][0] + boff;
#pragma unroll
            for (int i = 0; i < 4; ++i) {
                af[i] = *(const bf16x8*)(aB + i * 512);
                bq[i] = *(const bf16x8*)(bB + i * 512);
            }
            __builtin_amdgcn_s_setprio(1);
#pragma unroll
            for (int mf = 0; mf < 4; ++mf)
#pragma unroll
                for (int nf = 0; nf < 4; ++nf)
                    acc[mf][nf] = __builtin_amdgcn_mfma_f32_16x16x32_bf16(
                        af[mf], bq[nf], acc[mf][nf], 0, 0, 0);
            __builtin_amdgcn_s_setprio(0);
        }
        {
            const ushort* aB = &As[c][1][0] + aoff;
            const ushort* bB = &Bs[c][1][0] + boff;
#pragma unroll
            for (int i = 0; i < 4; ++i) {
                af[i] = *(const bf16x8*)(aB + i * 512);
                bq[i] = *(const bf16x8*)(bB + i * 512);
            }
            __builtin_amdgcn_s_setprio(1);
#pragma unroll
            for (int mf = 0; mf < 4; ++mf)
#pragma unroll
                for (int nf = 0; nf < 4; ++nf)
                    acc[mf][nf] = __builtin_amdgcn_mfma_f32_16x16x32_bf16(
                        af[mf], bq[nf], acc[mf][nf], 0, 0, 0);
            __builtin_amdgcn_s_setprio(0);
        }
    }

    // Epilogue: diagonal + per-(mf,r) softmax partial + 16-lane butterfly
#pragma unroll
    for (int mf = 0; mf < 4; ++mf)
#pragma unroll
        for (int r = 0; r < 4; ++r) {
            const int row_g = row0 + wr * 64 + mf * 16 + lhi * 4 + r;
#pragma unroll
            for (int nf = 0; nf < 4; ++nf) {
                const int col_g = col0 + wc * 64 + nf * 16 + l15;
                if (row_g == col_g) numer[row_g] = acc[mf][nf][r];
            }
            const float v0 = acc[mf][0][r], v1 = acc[mf][1][r];
            const float v2 = acc[mf][2][r], v3 = acc[mf][3][r];
            float m = fmaxf(fmaxf(v0, v1), fmaxf(v2, v3));
            float s = __expf(v0 - m) + __expf(v1 - m)
                    + __expf(v2 - m) + __expf(v3 - m);
#pragma unroll
            for (int off = 1; off < 16; off <<= 1) {
                const float mo = __shfl_xor(m, off, 64);
                const float so = __shfl_xor(s, off, 64);
                const float mn = fmaxf(m, mo);
                s = s * __expf(m - mn) + so * __expf(mo - mn);
                m = mn;
            }
            if (l15 == 0) {
                pm[row_g * NPART + cs * 4 + wc] = m;
                ps[row_g * NPART + cs * 4 + wc] = s;
            }
        }
}

// ---------------------------------------------------------------------------
// Pass 3a: one WAVE per row — coalesced partial combine + masked row loss
// ---------------------------------------------------------------------------
__global__ __launch_bounds__(256) void nce_finish_a(
    const int* __restrict__ tgt,
    const float* __restrict__ numer,
    const float* __restrict__ pm,
    const float* __restrict__ ps,
    float* __restrict__ bl_loss,
    float* __restrict__ bl_cnt,
    int npart)
{
    const int tid  = threadIdx.x;
    const int lane = tid & 63;
    const int wv   = tid >> 6;
    const int waves_total = gridDim.x * 4;

    float loss = 0.f, cnt = 0.f;

    for (int row = blockIdx.x * 4 + wv; row < N_TOK; row += waves_total) {
        if (tgt[row] != MASK_ID_V) continue;
        float pmv = -3.0e38f, psv = 0.f;
        if (lane < npart) {
            pmv = pm[row * npart + lane];
            psv = ps[row * npart + lane];
        }
        float m = pmv;
#pragma unroll
        for (int off = 32; off; off >>= 1) m = fmaxf(m, __shfl_xor(m, off, 64));
        float sv = psv * __expf(pmv - m);
#pragma unroll
        for (int off = 32; off; off >>= 1) sv += __shfl_xor(sv, off, 64);
        if (lane == 0) {
            loss += numer[row] - (m + __logf(sv));
            cnt  += 1.f;
        }
    }

    __shared__ float sl[4], sc[4];
    if (lane == 0) { sl[wv] = loss; sc[wv] = cnt; }
    __syncthreads();
    if (tid == 0) {
        bl_loss[blockIdx.x] = sl[0] + sl[1] + sl[2] + sl[3];
        bl_cnt[blockIdx.x]  = sc[0] + sc[1] + sc[2] + sc[3];
    }
}

__global__ __launch_bounds__(256) void nce_finish_b(
    const float* __restrict__ bl_loss,
    const float* __restrict__ bl_cnt,
    float* __restrict__ out, int nblk)
{
    const int tid = threadIdx.x;
    float l = 0.f, c = 0.f;
    for (int i = tid; i < nblk; i += 256) { l += bl_loss[i]; c += bl_cnt[i]; }
    __shared__ float sl[256], sc[256];
    sl[tid] = l; sc[tid] = c;
    __syncthreads();
    for (int off = 128; off; off >>= 1) {
        if (tid < off) { sl[tid] += sl[tid + off]; sc[tid] += sc[tid + off]; }
        __syncthreads();
    }
    if (tid == 0) out[0] = -(sl[0] / sc[0]);
}

// ---------------------------------------------------------------------------
// Fallback (on-the-fly convert) — only if ws too small
// ---------------------------------------------------------------------------
__global__ __launch_bounds__(256, 2) void nce_gemm_fb(
    const float* __restrict__ x, const float* __restrict__ emb,
    float* __restrict__ numer, float* __restrict__ pm, float* __restrict__ ps)
{
    __shared__ ushort At[BM][LDW];
    __shared__ ushort Bt[BN][LDW];

    const int rb = blockIdx.x, cs = blockIdx.y;
    const int row0 = rb * BM, col0 = cs * SLICE_W;
    const int tid = threadIdx.x, lane = tid & 63, wid = tid >> 6;
    const int wr = wid >> 1, wc = wid & 1, l15 = lane & 15, lhi = lane >> 4;

    float m_run[16], s_run[16];
#pragma unroll
    for (int i = 0; i < 16; ++i) { m_run[i] = -3.0e38f; s_run[i] = 0.0f; }

    for (int ct = 0; ct < CTS; ++ct) {
        const int colt0 = col0 + ct * BN;
        f32x4 acc[4][4];
#pragma unroll
        for (int a = 0; a < 4; ++a)
#pragma unroll
            for (int b = 0; b < 4; ++b) acc[a][b] = f32x4{0.f,0.f,0.f,0.f};

#pragma unroll 1
        for (int kt = 0; kt < KST; ++kt) {
            __syncthreads();
#pragma unroll
            for (int i = 0; i < 4; ++i) {
                const int chunk = tid + i * 256;
                const int r = chunk >> 3, c8 = (chunk & 7) << 3;
                const float* ga = emb + (size_t)(row0 + r) * D_DIM + kt * BK + c8;
                float4 a0 = *(const float4*)(ga); float4 a1 = *(const float4*)(ga + 4);
                uint4 pa;
                pa.x = pk2bf(a0.x, a0.y); pa.y = pk2bf(a0.z, a0.w);
                pa.z = pk2bf(a1.x, a1.y); pa.w = pk2bf(a1.z, a1.w);
                *(uint4*)&At[r][c8] = pa;
                const float* gb = x + (size_t)(colt0 + r) * D_DIM + kt * BK + c8;
                float4 b0 = *(const float4*)(gb); float4 b1 = *(const float4*)(gb + 4);
                uint4 pb;
                pb.x = pk2bf(b0.x, b0.y); pb.y = pk2bf(b0.z, b0.w);
                pb.z = pk2bf(b1.x, b1.y); pb.w = pk2bf(b1.z, b1.w);
                *(uint4*)&Bt[r][c8] = pb;
            }
            __syncthreads();
#pragma unroll
            for (int kp = 0; kp < 2; ++kp) {
                const int ko = kp * 32 + lhi * 8;
                bf16x8 af[4], bfr[4];
#pragma unroll
                for (int mi = 0; mi < 4; ++mi)
                    af[mi] = *(const bf16x8*)&At[wr*64 + mi*16 + l15][ko];
#pragma unroll
                for (int ni = 0; ni < 4; ++ni)
                    bfr[ni] = *(const bf16x8*)&Bt[wc*64 + ni*16 + l15][ko];
#pragma unroll
                for (int mi = 0; mi < 4; ++mi)
#pragma unroll
                    for (int ni = 0; ni < 4; ++ni)
                        acc[mi][ni] = __builtin_amdgcn_mfma_f32_16x16x32_bf16(
                            af[mi], bfr[ni], acc[mi][ni], 0, 0, 0);
            }
        }

#pragma unroll
        for (int mi = 0; mi < 4; ++mi)
#pragma unroll
            for (int r = 0; r < 4; ++r) {
                const int row_g = row0 + wr*64 + mi*16 + lhi*4 + r;
#pragma unroll
                for (int ni = 0; ni < 4; ++ni) {
                    const int col_g = colt0 + wc*64 + ni*16 + l15;
                    if (row_g == col_g) numer[row_g] = acc[mi][ni][r];
                }
                const int idx = mi * 4 + r;
                const float v0 = acc[mi][0][r], v1 = acc[mi][1][r];
                const float v2 = acc[mi][2][r], v3 = acc[mi][3][r];
                const float mx = fmaxf(fmaxf(v0, v1), fmaxf(v2, v3));
                const float mn = fmaxf(m_run[idx], mx);
                const float scale = __expf(m_run[idx] - mn);
                s_run[idx] = s_run[idx] * scale
                           + __expf(v0 - mn) + __expf(v1 - mn)
                           + __expf(v2 - mn) + __expf(v3 - mn);
                m_run[idx] = mn;
            }
    }

#pragma unroll
    for (int idx = 0; idx < 16; ++idx) {
        float m = m_run[idx], s = s_run[idx];
#pragma unroll
        for (int off = 1; off < 16; off <<= 1) {
            const float mo = __shfl_xor(m, off, 64);
            const float so = __shfl_xor(s, off, 64);
            const float mn = fmaxf(m, mo);
            s = s * __expf(m - mn) + so * __expf(mo - mn);
            m = mn;
        }
        m_run[idx] = m; s_run[idx] = s;
    }

    if (l15 == 0) {
        const int slot = cs * 2 + wc;
#pragma unroll
        for (int mi = 0; mi < 4; ++mi)
#pragma unroll
            for (int r = 0; r < 4; ++r) {
                const int row_g = row0 + wr*64 + mi*16 + lhi*4 + r;
                pm[row_g * NPART_FB + slot] = m_run[mi*4 + r];
                ps[row_g * NPART_FB + slot] = s_run[mi*4 + r];
            }
    }
}

extern "C" void kernel_launch(void* const* d_in, const int* in_sizes, int n_in,
                              void* d_out, int out_size, void* d_ws, size_t ws_size,
                              hipStream_t stream) {
    (void)in_sizes; (void)n_in; (void)out_size;
    const float* x   = (const float*)d_in[0];
    const float* emb = (const float*)d_in[1];
    const int*   tgt = (const int*)d_in[2];
    float* out = (float*)d_out;

    const size_t elems = (size_t)N_TOK * D_DIM;
    const size_t need  = elems * 2 * 2
                       + (size_t)N_TOK * 4
                       + (size_t)N_TOK * NPART * 4 * 2
                       + FIN_BLOCKS * 8;

    if (ws_size >= need) {
        ushort* xb    = (ushort*)d_ws;
        ushort* eb    = xb + elems;
        float*  numer = (float*)(eb + elems);
        float*  pm    = numer + N_TOK;
        float*  ps    = pm + (size_t)N_TOK * NPART;
        float*  bl    = ps + (size_t)N_TOK * NPART;
        float*  bc    = bl + FIN_BLOCKS;

        conv_bf16<<<1024, 256, 0, stream>>>(x, emb, xb, eb);
        nce_gemm8<<<NSL2 * NSL2, 1024, 0, stream>>>(xb, eb, numer, pm, ps);
        nce_finish_a<<<FIN_BLOCKS, 256, 0, stream>>>(tgt, numer, pm, ps, bl, bc, NPART);
        nce_finish_b<<<1, 256, 0, stream>>>(bl, bc, out, FIN_BLOCKS);
    } else {
        float* numer = (float*)d_ws;
        float* pm    = numer + N_TOK;
        float* ps    = pm + (size_t)N_TOK * NPART_FB;
        float* bl    = ps + (size_t)N_TOK * NPART_FB;
        float* bc    = bl + FIN_BLOCKS;
        nce_gemm_fb<<<dim3(N_TOK / BM, NSLICE_FB), 256, 0, stream>>>(x, emb, numer, pm, ps);
        nce_finish_a<<<FIN_BLOCKS, 256, 0, stream>>>(tgt, numer, pm, ps, bl, bc, NPART_FB);
        nce_finish_b<<<1, 256, 0, stream>>>(bl, bc, out, FIN_BLOCKS);
    }
}

// Round 8
// 49.426 us; speedup vs baseline: 1.1563x; 1.1563x over previous
//
#include <hip/hip_runtime.h>
#include <hip/hip_bf16.h>
#include <stdint.h>

// Problem constants (B=8, S=512, D=1024)
constexpr int N_TOK  = 4096;   // B*S
constexpr int D_DIM  = 1024;
constexpr int MASK_ID_V = 8192;

// Fast path: 256x256 tiles, 16 waves (4Mx4N), fp8 MX (32x32x64 scaled MFMA)
constexpr int BM2  = 256;
constexpr int KIT  = D_DIM / 128;    // 8 staged K-iters of 128
constexpr int NSL2 = N_TOK / BM2;    // 16 col slices
constexpr int NPART = NSL2 * 4;      // 64 partials/row

constexpr float SCALE   = 64.0f;     // pre-scale into e4m3 normal range
constexpr float INVSC2  = 1.0f / (SCALE * SCALE);

// Fallback tiling (used only if ws too small)
constexpr int BM = 128, BN = 128, BK = 64;
constexpr int KST = D_DIM / BK;
constexpr int NSLICE_FB = 8;
constexpr int SLICE_W   = N_TOK / NSLICE_FB;
constexpr int CTS       = SLICE_W / BN;
constexpr int LDW       = BK + 8;
constexpr int NPART_FB  = NSLICE_FB * 2;

constexpr int FIN_BLOCKS = 256;

typedef __attribute__((ext_vector_type(4)))  float f32x4;
typedef __attribute__((ext_vector_type(16))) float f32x16;
typedef __attribute__((ext_vector_type(8)))  short bf16x8;
typedef __attribute__((ext_vector_type(8)))  int   i32x8;

__device__ __forceinline__ uint32_t pk2bf(float lo, float hi) {
    union { float f; uint32_t u; } a, b;
    a.f = lo; b.f = hi;
    uint32_t ua = (a.u + 0x7fffu + ((a.u >> 16) & 1u)) >> 16;
    uint32_t ub = (b.u + 0x7fffu + ((b.u >> 16) & 1u)) >> 16;
    return ua | (ub << 16);
}

__device__ __forceinline__ void async16(void* lds, const void* g) {
    __builtin_amdgcn_global_load_lds(
        (const __attribute__((address_space(1))) uint32_t*)g,
        (__attribute__((address_space(3))) uint32_t*)lds,
        16, 0, 0);
}

#define BAR do { __builtin_amdgcn_s_barrier(); __builtin_amdgcn_sched_barrier(0); } while (0)

// ---------------------------------------------------------------------------
// Pass 1: fp32 -> fp8 e4m3 (OCP) pre-convert with fixed x64 pre-scale
// ---------------------------------------------------------------------------
__device__ __forceinline__ uint pk4fp8(float4 v) {
    int w = __builtin_amdgcn_cvt_pk_fp8_f32(v.x * SCALE, v.y * SCALE, 0, false);
    w = __builtin_amdgcn_cvt_pk_fp8_f32(v.z * SCALE, v.w * SCALE, w, true);
    return (uint)w;
}

__global__ __launch_bounds__(256) void conv_fp8(
    const float* __restrict__ x, const float* __restrict__ e,
    unsigned char* __restrict__ xb8, unsigned char* __restrict__ eb8)
{
    constexpr int NC = N_TOK * D_DIM / 16;   // 16 elems per chunk
    const int t0 = blockIdx.x * blockDim.x + threadIdx.x;
    const int stride = gridDim.x * blockDim.x;
    for (int c = t0; c < NC; c += stride) {
        const float4* px = (const float4*)x + (size_t)c * 4;
        uint4 o;
        o.x = pk4fp8(px[0]); o.y = pk4fp8(px[1]);
        o.z = pk4fp8(px[2]); o.w = pk4fp8(px[3]);
        ((uint4*)xb8)[c] = o;

        const float4* pe = (const float4*)e + (size_t)c * 4;
        uint4 q;
        q.x = pk4fp8(pe[0]); q.y = pk4fp8(pe[1]);
        q.z = pk4fp8(pe[2]); q.w = pk4fp8(pe[3]);
        ((uint4*)eb8)[c] = q;
    }
}

// ---------------------------------------------------------------------------
// Pass 2: 256x256 fp8 MX GEMM (32x32x64 scaled MFMA, uniform scale=1.0),
// double-buffered gload_lds staging with involution XOR swizzle, + online lse
// ---------------------------------------------------------------------------
__device__ __forceinline__ i32x8 ld_frag(const unsigned char* base, int o0, int o1) {
    uint4 u = *(const uint4*)(base + o0);
    uint4 v = *(const uint4*)(base + o1);
    i32x8 r = { (int)u.x, (int)u.y, (int)u.z, (int)u.w,
                (int)v.x, (int)v.y, (int)v.z, (int)v.w };
    return r;
}

__global__ __launch_bounds__(1024, 4) void nce_gemm_fp8(
    const unsigned char* __restrict__ xb8,   // [N_TOK][1024] fp8 keys (x * 64)
    const unsigned char* __restrict__ eb8,   // [N_TOK][1024] fp8 queries
    float* __restrict__ numer,
    float* __restrict__ pm,
    float* __restrict__ ps)
{
    __shared__ unsigned char As[2][32768];   // [buf][256*128] fp8  64 KB
    __shared__ unsigned char Bs[2][32768];   // 64 KB  (total 128 KB)

    // Bijective XCD-chunked swizzle: each XCD -> two 4x4 tile-chunks
    const int bid   = blockIdx.x;
    const int sw    = (bid & 7) * 32 + (bid >> 3);
    const int chunk = sw >> 4, win = sw & 15;
    const int rb    = (chunk & 3) * 4 + (win & 3);
    const int cs    = (chunk >> 2) * 4 + (win >> 2);
    const int row0  = rb * BM2;
    const int col0  = cs * BM2;

    const int tid  = threadIdx.x;
    const int lane = tid & 63;
    const int wid  = tid >> 6;         // 0..15
    const int wr   = wid >> 2;         // 0..3  (M-warps, 64 rows each)
    const int wc   = wid & 3;          // 0..3  (N-warps, 64 cols each)
    const int l31  = lane & 31;
    const int lg   = lane >> 5;        // 0..1  (k-group / row-half)

    // Staging: chunk q = (wid*2+s)*64 + lane; row = q>>3; phys slot = q&7;
    // source col-chunk = (q&7) ^ (row&7)  (involution both-sides swizzle)
    const int q0_ = wid * 128 + lane;
    const int q1_ = q0_ + 64;
    const int r0_ = q0_ >> 3, c0_ = (q0_ & 7) ^ (r0_ & 7);
    const int r1_ = q1_ >> 3, c1_ = (q1_ & 7) ^ (r1_ & 7);
    const unsigned char* gA0 = eb8 + (size_t)(row0 + r0_) * D_DIM + c0_ * 16;
    const unsigned char* gA1 = eb8 + (size_t)(row0 + r1_) * D_DIM + c1_ * 16;
    const unsigned char* gB0 = xb8 + (size_t)(col0 + r0_) * D_DIM + c0_ * 16;
    const unsigned char* gB1 = xb8 + (size_t)(col0 + r1_) * D_DIM + c1_ * 16;

    // Frag read offsets: row rX, logical slot = ks*4 + lg*2 + j, phys ^= row&7.
    const int rA = wr * 64 + l31;                 // fr adds 32 (doesn't change row&7)
    const int pA = (lg * 2) ^ (rA & 7);
    const int rB = wc * 64 + l31;
    const int pB = (lg * 2) ^ (rB & 7);
    int offA[2][2], offB[2][2];
#pragma unroll
    for (int ks = 0; ks < 2; ++ks)
#pragma unroll
        for (int j = 0; j < 2; ++j) {
            offA[ks][j] = rA * 128 + ((pA ^ (ks << 2) ^ j) << 4);
            offB[ks][j] = rB * 128 + ((pB ^ (ks << 2) ^ j) << 4);
        }

    f32x16 acc00 = {0.f}, acc01 = {0.f}, acc10 = {0.f}, acc11 = {0.f};
#pragma unroll
    for (int i = 0; i < 16; ++i) { acc00[i] = 0.f; acc01[i] = 0.f; acc10[i] = 0.f; acc11[i] = 0.f; }

    // Prologue: stage K-iter 0 into buffer 0
    async16(As[0] + wid * 2048,        gA0);
    async16(As[0] + wid * 2048 + 1024, gA1);
    async16(Bs[0] + wid * 2048,        gB0);
    async16(Bs[0] + wid * 2048 + 1024, gB1);

#pragma unroll 1
    for (int kt = 0; kt < KIT; ++kt) {
        const int c = kt & 1, n = c ^ 1;
        const bool pre = (kt < KIT - 1);

        asm volatile("s_waitcnt vmcnt(0)" ::: "memory");
        BAR;

        if (pre) {
            const int ko = (kt + 1) * 128;
            async16(As[n] + wid * 2048,        gA0 + ko);
            async16(As[n] + wid * 2048 + 1024, gA1 + ko);
            async16(Bs[n] + wid * 2048,        gB0 + ko);
            async16(Bs[n] + wid * 2048 + 1024, gB1 + ko);
        }

        const unsigned char* Ab = As[c];
        const unsigned char* Bb = Bs[c];
#pragma unroll
        for (int ks = 0; ks < 2; ++ks) {
            i32x8 a0 = ld_frag(Ab,        offA[ks][0], offA[ks][1]);
            i32x8 a1 = ld_frag(Ab + 4096, offA[ks][0], offA[ks][1]);
            i32x8 b0 = ld_frag(Bb,        offB[ks][0], offB[ks][1]);
            i32x8 b1 = ld_frag(Bb + 4096, offB[ks][0], offB[ks][1]);
            __builtin_amdgcn_s_setprio(1);
            acc00 = __builtin_amdgcn_mfma_scale_f32_32x32x64_f8f6f4(
                a0, b0, acc00, 0, 0, 0, 127, 0, 127);
            acc01 = __builtin_amdgcn_mfma_scale_f32_32x32x64_f8f6f4(
                a0, b1, acc01, 0, 0, 0, 127, 0, 127);
            acc10 = __builtin_amdgcn_mfma_scale_f32_32x32x64_f8f6f4(
                a1, b0, acc10, 0, 0, 0, 127, 0, 127);
            acc11 = __builtin_amdgcn_mfma_scale_f32_32x32x64_f8f6f4(
                a1, b1, acc11, 0, 0, 0, 127, 0, 127);
            __builtin_amdgcn_s_setprio(0);
        }
    }

    // Epilogue. 32x32 C/D layout: col = lane&31, row = (reg&3)+8*(reg>>2)+4*lg.
    const int c0g = col0 + wc * 64 + l31;        // fc=0 col
    const int c1g = c0g + 32;                    // fc=1 col

#pragma unroll
    for (int reg = 0; reg < 16; ++reg) {
        const int rif = (reg & 3) + 8 * (reg >> 2) + 4 * lg;
#pragma unroll
        for (int fr = 0; fr < 2; ++fr) {
            const int row_g = row0 + wr * 64 + fr * 32 + rif;
            const float v0 = (fr ? acc10[reg] : acc00[reg]) * INVSC2;
            const float v1 = (fr ? acc11[reg] : acc01[reg]) * INVSC2;
            if (row_g == c0g) numer[row_g] = v0;
            if (row_g == c1g) numer[row_g] = v1;
            float m = fmaxf(v0, v1);
#pragma unroll
            for (int off = 1; off <= 16; off <<= 1)
                m = fmaxf(m, __shfl_xor(m, off, 64));
            float s = __expf(v0 - m) + __expf(v1 - m);
#pragma unroll
            for (int off = 1; off <= 16; off <<= 1)
                s += __shfl_xor(s, off, 64);
            if (l31 == 0) {
                pm[row_g * NPART + cs * 4 + wc] = m;
                ps[row_g * NPART + cs * 4 + wc] = s;
            }
        }
    }
}

// ---------------------------------------------------------------------------
// Pass 3a: one WAVE per row — coalesced partial combine + masked row loss
// ---------------------------------------------------------------------------
__global__ __launch_bounds__(256) void nce_finish_a(
    const int* __restrict__ tgt,
    const float* __restrict__ numer,
    const float* __restrict__ pm,
    const float* __restrict__ ps,
    float* __restrict__ bl_loss,
    float* __restrict__ bl_cnt,
    int npart)
{
    const int tid  = threadIdx.x;
    const int lane = tid & 63;
    const int wv   = tid >> 6;
    const int waves_total = gridDim.x * 4;

    float loss = 0.f, cnt = 0.f;

    for (int row = blockIdx.x * 4 + wv; row < N_TOK; row += waves_total) {
        if (tgt[row] != MASK_ID_V) continue;
        float pmv = -3.0e38f, psv = 0.f;
        if (lane < npart) {
            pmv = pm[row * npart + lane];
            psv = ps[row * npart + lane];
        }
        float m = pmv;
#pragma unroll
        for (int off = 32; off; off >>= 1) m = fmaxf(m, __shfl_xor(m, off, 64));
        float sv = psv * __expf(pmv - m);
#pragma unroll
        for (int off = 32; off; off >>= 1) sv += __shfl_xor(sv, off, 64);
        if (lane == 0) {
            loss += numer[row] - (m + __logf(sv));
            cnt  += 1.f;
        }
    }

    __shared__ float sl[4], sc[4];
    if (lane == 0) { sl[wv] = loss; sc[wv] = cnt; }
    __syncthreads();
    if (tid == 0) {
        bl_loss[blockIdx.x] = sl[0] + sl[1] + sl[2] + sl[3];
        bl_cnt[blockIdx.x]  = sc[0] + sc[1] + sc[2] + sc[3];
    }
}

__global__ __launch_bounds__(256) void nce_finish_b(
    const float* __restrict__ bl_loss,
    const float* __restrict__ bl_cnt,
    float* __restrict__ out, int nblk)
{
    const int tid = threadIdx.x;
    float l = 0.f, c = 0.f;
    for (int i = tid; i < nblk; i += 256) { l += bl_loss[i]; c += bl_cnt[i]; }
    __shared__ float sl[256], sc[256];
    sl[tid] = l; sc[tid] = c;
    __syncthreads();
    for (int off = 128; off; off >>= 1) {
        if (tid < off) { sl[tid] += sl[tid + off]; sc[tid] += sc[tid + off]; }
        __syncthreads();
    }
    if (tid == 0) out[0] = -(sl[0] / sc[0]);
}

// ---------------------------------------------------------------------------
// Fallback (bf16 on-the-fly convert) — only if ws too small
// ---------------------------------------------------------------------------
__global__ __launch_bounds__(256, 2) void nce_gemm_fb(
    const float* __restrict__ x, const float* __restrict__ emb,
    float* __restrict__ numer, float* __restrict__ pm, float* __restrict__ ps)
{
    __shared__ ushort At[BM][LDW];
    __shared__ ushort Bt[BN][LDW];

    const int rb = blockIdx.x, cs = blockIdx.y;
    const int row0 = rb * BM, col0 = cs * SLICE_W;
    const int tid = threadIdx.x, lane = tid & 63, wid = tid >> 6;
    const int wr = wid >> 1, wc = wid & 1, l15 = lane & 15, lhi = lane >> 4;

    float m_run[16], s_run[16];
#pragma unroll
    for (int i = 0; i < 16; ++i) { m_run[i] = -3.0e38f; s_run[i] = 0.0f; }

    for (int ct = 0; ct < CTS; ++ct) {
        const int colt0 = col0 + ct * BN;
        f32x4 acc[4][4];
#pragma unroll
        for (int a = 0; a < 4; ++a)
#pragma unroll
            for (int b = 0; b < 4; ++b) acc[a][b] = f32x4{0.f,0.f,0.f,0.f};

#pragma unroll 1
        for (int kt = 0; kt < KST; ++kt) {
            __syncthreads();
#pragma unroll
            for (int i = 0; i < 4; ++i) {
                const int chunk = tid + i * 256;
                const int r = chunk >> 3, c8 = (chunk & 7) << 3;
                const float* ga = emb + (size_t)(row0 + r) * D_DIM + kt * BK + c8;
                float4 a0 = *(const float4*)(ga); float4 a1 = *(const float4*)(ga + 4);
                uint4 pa;
                pa.x = pk2bf(a0.x, a0.y); pa.y = pk2bf(a0.z, a0.w);
                pa.z = pk2bf(a1.x, a1.y); pa.w = pk2bf(a1.z, a1.w);
                *(uint4*)&At[r][c8] = pa;
                const float* gb = x + (size_t)(colt0 + r) * D_DIM + kt * BK + c8;
                float4 b0 = *(const float4*)(gb); float4 b1 = *(const float4*)(gb + 4);
                uint4 pb;
                pb.x = pk2bf(b0.x, b0.y); pb.y = pk2bf(b0.z, b0.w);
                pb.z = pk2bf(b1.x, b1.y); pb.w = pk2bf(b1.z, b1.w);
                *(uint4*)&Bt[r][c8] = pb;
            }
            __syncthreads();
#pragma unroll
            for (int kp = 0; kp < 2; ++kp) {
                const int ko = kp * 32 + lhi * 8;
                bf16x8 af[4], bfr[4];
#pragma unroll
                for (int mi = 0; mi < 4; ++mi)
                    af[mi] = *(const bf16x8*)&At[wr*64 + mi*16 + l15][ko];
#pragma unroll
                for (int ni = 0; ni < 4; ++ni)
                    bfr[ni] = *(const bf16x8*)&Bt[wc*64 + ni*16 + l15][ko];
#pragma unroll
                for (int mi = 0; mi < 4; ++mi)
#pragma unroll
                    for (int ni = 0; ni < 4; ++ni)
                        acc[mi][ni] = __builtin_amdgcn_mfma_f32_16x16x32_bf16(
                            af[mi], bfr[ni], acc[mi][ni], 0, 0, 0);
            }
        }

#pragma unroll
        for (int mi = 0; mi < 4; ++mi)
#pragma unroll
            for (int r = 0; r < 4; ++r) {
                const int row_g = row0 + wr*64 + mi*16 + lhi*4 + r;
#pragma unroll
                for (int ni = 0; ni < 4; ++ni) {
                    const int col_g = colt0 + wc*64 + ni*16 + l15;
                    if (row_g == col_g) numer[row_g] = acc[mi][ni][r];
                }
                const int idx = mi * 4 + r;
                const float v0 = acc[mi][0][r], v1 = acc[mi][1][r];
                const float v2 = acc[mi][2][r], v3 = acc[mi][3][r];
                const float mx = fmaxf(fmaxf(v0, v1), fmaxf(v2, v3));
                const float mn = fmaxf(m_run[idx], mx);
                const float scale = __expf(m_run[idx] - mn);
                s_run[idx] = s_run[idx] * scale
                           + __expf(v0 - mn) + __expf(v1 - mn)
                           + __expf(v2 - mn) + __expf(v3 - mn);
                m_run[idx] = mn;
            }
    }

#pragma unroll
    for (int idx = 0; idx < 16; ++idx) {
        float m = m_run[idx], s = s_run[idx];
#pragma unroll
        for (int off = 1; off < 16; off <<= 1) {
            const float mo = __shfl_xor(m, off, 64);
            const float so = __shfl_xor(s, off, 64);
            const float mn = fmaxf(m, mo);
            s = s * __expf(m - mn) + so * __expf(mo - mn);
            m = mn;
        }
        m_run[idx] = m; s_run[idx] = s;
    }

    if (l15 == 0) {
        const int slot = cs * 2 + wc;
#pragma unroll
        for (int mi = 0; mi < 4; ++mi)
#pragma unroll
            for (int r = 0; r < 4; ++r) {
                const int row_g = row0 + wr*64 + mi*16 + lhi*4 + r;
                pm[row_g * NPART_FB + slot] = m_run[mi*4 + r];
                ps[row_g * NPART_FB + slot] = s_run[mi*4 + r];
            }
    }
}

extern "C" void kernel_launch(void* const* d_in, const int* in_sizes, int n_in,
                              void* d_out, int out_size, void* d_ws, size_t ws_size,
                              hipStream_t stream) {
    (void)in_sizes; (void)n_in; (void)out_size;
    const float* x   = (const float*)d_in[0];
    const float* emb = (const float*)d_in[1];
    const int*   tgt = (const int*)d_in[2];
    float* out = (float*)d_out;

    const size_t elems = (size_t)N_TOK * D_DIM;
    const size_t need  = elems * 2                       // xb8 + eb8 (fp8)
                       + (size_t)N_TOK * 4               // numer
                       + (size_t)N_TOK * NPART * 4 * 2   // pm + ps
                       + FIN_BLOCKS * 8;

    if (ws_size >= need) {
        unsigned char* xb8 = (unsigned char*)d_ws;
        unsigned char* eb8 = xb8 + elems;
        float* numer = (float*)(eb8 + elems);
        float* pm    = numer + N_TOK;
        float* ps    = pm + (size_t)N_TOK * NPART;
        float* bl    = ps + (size_t)N_TOK * NPART;
        float* bc    = bl + FIN_BLOCKS;

        conv_fp8<<<1024, 256, 0, stream>>>(x, emb, xb8, eb8);
        nce_gemm_fp8<<<NSL2 * NSL2, 1024, 0, stream>>>(xb8, eb8, numer, pm, ps);
        nce_finish_a<<<FIN_BLOCKS, 256, 0, stream>>>(tgt, numer, pm, ps, bl, bc, NPART);
        nce_finish_b<<<1, 256, 0, stream>>>(bl, bc, out, FIN_BLOCKS);
    } else {
        float* numer = (float*)d_ws;
        float* pm    = numer + N_TOK;
        float* ps    = pm + (size_t)N_TOK * NPART_FB;
        float* bl    = ps + (size_t)N_TOK * NPART_FB;
        float* bc    = bl + FIN_BLOCKS;
        nce_gemm_fb<<<dim3(N_TOK / BM, NSLICE_FB), 256, 0, stream>>>(x, emb, numer, pm, ps);
        nce_finish_a<<<FIN_BLOCKS, 256, 0, stream>>>(tgt, numer, pm, ps, bl, bc, NPART_FB);
        nce_finish_b<<<1, 256, 0, stream>>>(bl, bc, out, FIN_BLOCKS);
    }
}